// Round 3
// baseline (432.290 us; speedup 1.0000x reference)
//
#include <hip/hip_runtime.h>

// ---------------- problem constants ----------------
#define BATCH   4
#define S_LEN   2048
#define DMODEL  1024
#define NHEAD   16
#define DKH     64          // head dim
#define GM      8192        // BATCH*S_LEN
#define GN      1024
#define GK      1024
#define BM      128
#define BN      128
#define BK      32
#define KTILES  (GK / BK)   // 32

typedef unsigned short u16;
typedef unsigned int   u32;
typedef __attribute__((ext_vector_type(8))) short  short8;  // MFMA a/b frag (guide-verified type)
typedef __attribute__((ext_vector_type(4))) float  f32x4;

// round-to-nearest-even fp32 -> bf16 (raw bits)
__device__ __forceinline__ u16 f2bf(float f) {
    u32 u = __builtin_bit_cast(u32, f);
    u32 r = (u + 0x7fffu + ((u >> 16) & 1u)) >> 16;
    return (u16)r;
}

// async global->LDS, 16B per lane. LDS dest MUST be wave-uniform (HW adds lane*16).
__device__ __forceinline__ void gload_lds16(const u16* g, u16* l) {
    __builtin_amdgcn_global_load_lds(
        (const __attribute__((address_space(1))) u32*)g,
        (__attribute__((address_space(3))) u32*)l,
        16, 0, 0);
}

// ---------------- cast fp32 -> bf16 ----------------
__global__ void cast_kernel(const float* __restrict__ x,  const float* __restrict__ wq,
                            const float* __restrict__ wk, const float* __restrict__ wv,
                            const float* __restrict__ wo,
                            u16* __restrict__ xb,  u16* __restrict__ wqb,
                            u16* __restrict__ wkb, u16* __restrict__ wvb,
                            u16* __restrict__ wob) {
    const int X4 = BATCH * S_LEN * DMODEL / 4;   // 2097152
    const int W4 = DMODEL * DMODEL / 4;          // 262144 = 2^18
    const int total4 = X4 + 4 * W4;
    for (int i = blockIdx.x * blockDim.x + threadIdx.x; i < total4;
         i += gridDim.x * blockDim.x) {
        const float* src; u16* dst; int off;
        if (i < X4) { src = x; dst = xb; off = i; }
        else {
            int j = i - X4;
            int sel = j >> 18;
            off = j & (W4 - 1);
            src = sel == 0 ? wq : sel == 1 ? wk : sel == 2 ? wv : wo;
            dst = sel == 0 ? wqb : sel == 1 ? wkb : sel == 2 ? wvb : wob;
        }
        float4 v = ((const float4*)src)[off];
        ushort4 o;
        o.x = f2bf(v.x); o.y = f2bf(v.y); o.z = f2bf(v.z); o.w = f2bf(v.w);
        ((ushort4*)dst)[off] = o;
    }
}

// ---------------- GEMM: C[M,N] = A[M,K] * W[N,K]^T ----------------
// MODE 0: bf16 out, layout [B,H,S,DK]   (Q, K)
// MODE 1: bf16 out, layout [B,H,DK,S]   (V transposed)
// MODE 2: fp32 out [M,N] + bias         (final projection)
// LDS tile rows are 64B (4x16B slots); physical slot = logical ^ ((row>>1)&3).
// G21: linear LDS dest + inverse-swizzled GLOBAL source + swizzled ds_read.
template<int MODE>
__global__ __launch_bounds__(256) void gemm_bt(const u16* __restrict__ A,
                                               const u16* __restrict__ W,
                                               void* __restrict__ outp,
                                               const float* __restrict__ bias) {
    __shared__ __align__(16) u16 As[2][BM * BK];
    __shared__ __align__(16) u16 Ws[2][BN * BK];

    const int tid  = threadIdx.x;
    const int lane = tid & 63;
    const int wr   = (tid >> 6) >> 1;   // wave row (0..1)
    const int wc   = (tid >> 6) & 1;    // wave col (0..1)
    const int m0   = blockIdx.x * BM;
    const int n0   = blockIdx.y * BN;

    f32x4 acc[4][4] = {};

    auto stage = [&](int buf, int kt) {
        const int k0 = kt * BK;
#pragma unroll
        for (int j = 0; j < 2; ++j) {
            int c = j * 256 + tid;              // per-lane chunk id (global source)
            int wu = j * 256 + (tid & 192);     // wave-uniform LDS base chunk
            int row = c >> 2, slot = c & 3;
            int sg = slot ^ ((row >> 1) & 3);
            gload_lds16(A + (size_t)(m0 + row) * GK + k0 + sg * 8, &As[buf][wu * 8]);
        }
#pragma unroll
        for (int j = 0; j < 2; ++j) {
            int c = j * 256 + tid;
            int wu = j * 256 + (tid & 192);
            int row = c >> 2, slot = c & 3;
            int sg = slot ^ ((row >> 1) & 3);
            gload_lds16(W + (size_t)(n0 + row) * GK + k0 + sg * 8, &Ws[buf][wu * 8]);
        }
    };

    stage(0, 0);
    __syncthreads();

    for (int kt = 0; kt < KTILES; ++kt) {
        if (kt + 1 < KTILES) stage((kt + 1) & 1, kt + 1);

        const u16* ab = As[kt & 1];
        const u16* wb = Ws[kt & 1];
        const int ls = lane >> 4;           // logical k-slot (8 bf16 each)
        short8 af[4], wf[4];
#pragma unroll
        for (int mi = 0; mi < 4; ++mi) {
            int row = wr * 64 + mi * 16 + (lane & 15);
            int ps = ls ^ ((row >> 1) & 3);
            af[mi] = *(const short8*)(ab + row * BK + ps * 8);
        }
#pragma unroll
        for (int ni = 0; ni < 4; ++ni) {
            int row = wc * 64 + ni * 16 + (lane & 15);
            int ps = ls ^ ((row >> 1) & 3);
            wf[ni] = *(const short8*)(wb + row * BK + ps * 8);
        }
#pragma unroll
        for (int mi = 0; mi < 4; ++mi)
#pragma unroll
            for (int ni = 0; ni < 4; ++ni)
                acc[mi][ni] = __builtin_amdgcn_mfma_f32_16x16x32_bf16(
                    af[mi], wf[ni], acc[mi][ni], 0, 0, 0);

        __syncthreads();   // drains vmcnt (staged tile ready) + protects buffer reuse
    }

    // epilogue: C row = (lane>>4)*4 + r, col = lane&15 within each 16x16 frag
#pragma unroll
    for (int mi = 0; mi < 4; ++mi) {
#pragma unroll
        for (int ni = 0; ni < 4; ++ni) {
#pragma unroll
            for (int r = 0; r < 4; ++r) {
                int m = m0 + wr * 64 + mi * 16 + (lane >> 4) * 4 + r;
                int n = n0 + wc * 64 + ni * 16 + (lane & 15);
                float v = acc[mi][ni][r];
                if (MODE == 2) {
                    ((float*)outp)[(size_t)m * GN + n] = v + bias[n];
                } else {
                    int b = m >> 11, s = m & (S_LEN - 1);
                    int h = n >> 6,  d = n & (DKH - 1);
                    size_t idx;
                    if (MODE == 0)
                        idx = (((size_t)(b * NHEAD + h)) * S_LEN + s) * DKH + d;
                    else
                        idx = (((size_t)(b * NHEAD + h)) * DKH + d) * S_LEN + s;
                    ((u16*)outp)[idx] = f2bf(v);
                }
            }
        }
    }
}

// ---------------- flash attention (causal) ----------------
// grid (S/64, B*H), 256 threads (4 waves x 16 q-rows).
// Heavy q-tiles (more KV iterations) are dispatched FIRST (LPT scheduling):
// qt = 31 - blockIdx.x, so tail is backfilled by cheap blocks.
// Q,K: [B,H,S,DK] bf16; Vt: [B,H,DK,S] bf16; O: [B,S,D] bf16.
// K/V tiles in LDS, row stride 128B (8x16B slots), physical slot = logical ^ (row&7).
__global__ __launch_bounds__(256) void attn_kernel(const u16* __restrict__ Q,
                                                   const u16* __restrict__ Kx,
                                                   const u16* __restrict__ Vt,
                                                   u16* __restrict__ O) {
    __shared__ __align__(16) u16 Ks[64 * 64];
    __shared__ __align__(16) u16 Vs[64 * 64];
    __shared__ __align__(16) u16 Ps[4][16 * 72];   // padded rows: 144B -> conflict-free

    const int tid  = threadIdx.x;
    const int lane = tid & 63;
    const int wave = tid >> 6;
    const int qt   = (S_LEN / 64 - 1) - blockIdx.x;   // heavy tiles first
    const int bh   = blockIdx.y;        // 0..63
    const int b    = bh >> 4;
    const int h    = bh & 15;

    const size_t base = (size_t)bh * S_LEN * DKH;
    const u16* Qb = Q  + base;
    const u16* Kb = Kx + base;
    const u16* Vb = Vt + base;          // [DK][S]

    const int q0 = qt * 64;

    // Q fragments hoisted to registers (A operand: row = lane&15, k = (lane>>4)*8)
    short8 qf[2];
    {
        int qr = q0 + wave * 16 + (lane & 15);
#pragma unroll
        for (int kk = 0; kk < 2; ++kk)
            qf[kk] = *(const short8*)(Qb + (size_t)qr * DKH + kk * 32 + (lane >> 4) * 8);
    }

    f32x4 acc[4] = {};
    float mrow[4], lrow[4];
#pragma unroll
    for (int r = 0; r < 4; ++r) { mrow[r] = -1e30f; lrow[r] = 0.f; }

    const int nt = qt + 1;
    for (int t = 0; t < nt; ++t) {
        __syncthreads();    // all waves done reading previous K/V tile
        // stage K tile [key 64][dk 64] and V^T tile [dk 64][key 64]
#pragma unroll
        for (int j = 0; j < 2; ++j) {
            int c = j * 256 + tid;
            int wu = j * 256 + (tid & 192);
            int row = c >> 3, slot = c & 7;
            int sg = slot ^ (row & 7);
            gload_lds16(Kb + (size_t)(t * 64 + row) * DKH + sg * 8, &Ks[wu * 8]);
        }
#pragma unroll
        for (int j = 0; j < 2; ++j) {
            int c = j * 256 + tid;
            int wu = j * 256 + (tid & 192);
            int row = c >> 3, slot = c & 7;
            int sg = slot ^ (row & 7);
            gload_lds16(Vb + (size_t)row * S_LEN + t * 64 + sg * 8, &Vs[wu * 8]);
        }
        __syncthreads();    // staged data visible (syncthreads drains vmcnt)

        // ---- QK^T ----
        f32x4 sc[4] = {};
#pragma unroll
        for (int ni = 0; ni < 4; ++ni) {
#pragma unroll
            for (int kk = 0; kk < 2; ++kk) {
                int row = ni * 16 + (lane & 15);     // key row in tile
                int ps = (kk * 4 + (lane >> 4)) ^ (row & 7);
                short8 kf = *(const short8*)(Ks + row * 64 + ps * 8);
                sc[ni] = __builtin_amdgcn_mfma_f32_16x16x32_bf16(qf[kk], kf, sc[ni], 0, 0, 0);
            }
        }

        // ---- scale + causal mask ----
        const bool diag = (t == qt);
#pragma unroll
        for (int ni = 0; ni < 4; ++ni) {
#pragma unroll
            for (int r = 0; r < 4; ++r) {
                float s = sc[ni][r] * 0.125f;
                if (diag) {
                    int key = t * 64 + ni * 16 + (lane & 15);
                    int qr  = q0 + wave * 16 + (lane >> 4) * 4 + r;
                    if (key > qr) s = -1e30f;
                }
                sc[ni][r] = s;
            }
        }

        // ---- online softmax (per lane: 4 q-rows; reduce across 16-lane groups) ----
        float pv[4][4], alpha[4];
#pragma unroll
        for (int r = 0; r < 4; ++r) {
            float tm = fmaxf(fmaxf(sc[0][r], sc[1][r]), fmaxf(sc[2][r], sc[3][r]));
#pragma unroll
            for (int off = 1; off < 16; off <<= 1)
                tm = fmaxf(tm, __shfl_xor(tm, off));
            float mn = fmaxf(mrow[r], tm);
            alpha[r] = __expf(mrow[r] - mn);
            mrow[r] = mn;
            float rs = 0.f;
#pragma unroll
            for (int ni = 0; ni < 4; ++ni) {
                float p = __expf(sc[ni][r] - mn);
                pv[ni][r] = p;
                rs += p;
            }
#pragma unroll
            for (int off = 1; off < 16; off <<= 1)
                rs += __shfl_xor(rs, off);
            lrow[r] = lrow[r] * alpha[r] + rs;
        }
#pragma unroll
        for (int di = 0; di < 4; ++di)
#pragma unroll
            for (int r = 0; r < 4; ++r)
                acc[di][r] *= alpha[r];

        // ---- P -> LDS (per-wave buffer, intra-wave dependency only) ----
        u16* pw = Ps[wave];
#pragma unroll
        for (int ni = 0; ni < 4; ++ni)
#pragma unroll
            for (int r = 0; r < 4; ++r)
                pw[((lane >> 4) * 4 + r) * 72 + ni * 16 + (lane & 15)] = f2bf(pv[ni][r]);

        // ---- PV ----
#pragma unroll
        for (int kk = 0; kk < 2; ++kk) {
            short8 pa = *(const short8*)(pw + (lane & 15) * 72 + kk * 32 + (lane >> 4) * 8);
#pragma unroll
            for (int di = 0; di < 4; ++di) {
                int row = di * 16 + (lane & 15);     // dk row in V^T tile
                int ps = (kk * 4 + (lane >> 4)) ^ (row & 7);
                short8 vf = *(const short8*)(Vs + row * 64 + ps * 8);
                acc[di] = __builtin_amdgcn_mfma_f32_16x16x32_bf16(pa, vf, acc[di], 0, 0, 0);
            }
        }
    }

    // ---- epilogue: O[b][s][h*64+dk] ----
#pragma unroll
    for (int di = 0; di < 4; ++di)
#pragma unroll
        for (int r = 0; r < 4; ++r) {
            int s = q0 + wave * 16 + (lane >> 4) * 4 + r;
            int d = di * 16 + (lane & 15);
            float v = acc[di][r] / lrow[r];
            O[((size_t)b * S_LEN + s) * DMODEL + h * 64 + d] = f2bf(v);
        }
}

// ---------------- launcher ----------------
extern "C" void kernel_launch(void* const* d_in, const int* in_sizes, int n_in,
                              void* d_out, int out_size, void* d_ws, size_t ws_size,
                              hipStream_t stream) {
    const float* x  = (const float*)d_in[0];
    const float* wq = (const float*)d_in[1];
    const float* wk = (const float*)d_in[2];
    const float* wv = (const float*)d_in[3];
    const float* wo = (const float*)d_in[4];
    const float* bo = (const float*)d_in[5];

    const size_t XB  = (size_t)BATCH * S_LEN * DMODEL * 2;  // 16 MB
    const size_t WB  = (size_t)DMODEL * DMODEL * 2;         // 2 MB

    char* p = (char*)d_ws;
    u16* xb  = (u16*)p; p += XB;   // also reused as attention output Od (x dead after V GEMM)
    u16* wqb = (u16*)p; p += WB;
    u16* wkb = (u16*)p; p += WB;
    u16* wvb = (u16*)p; p += WB;
    u16* wob = (u16*)p; p += WB;
    u16* Qd  = (u16*)p; p += XB;
    u16* Kd  = (u16*)p; p += XB;
    u16* Vtd = (u16*)p; p += XB;
    u16* Od  = xb;
    // total workspace: 4*16MB + 4*2MB = 72 MB

    cast_kernel<<<2048, 256, 0, stream>>>(x, wq, wk, wv, wo, xb, wqb, wkb, wvb, wob);

    dim3 gg(GM / BM, GN / BN);   // 64 x 8
    gemm_bt<0><<<gg, 256, 0, stream>>>(xb, wqb, Qd,  nullptr);
    gemm_bt<0><<<gg, 256, 0, stream>>>(xb, wkb, Kd,  nullptr);
    gemm_bt<1><<<gg, 256, 0, stream>>>(xb, wvb, Vtd, nullptr);

    attn_kernel<<<dim3(S_LEN / 64, BATCH * NHEAD), 256, 0, stream>>>(Qd, Kd, Vtd, Od);

    gemm_bt<2><<<gg, 256, 0, stream>>>(Od, wob, d_out, bo);
}

// Round 4
// 341.571 us; speedup vs baseline: 1.2656x; 1.2656x over previous
//
#include <hip/hip_runtime.h>

// ---------------- problem constants ----------------
#define BATCH   4
#define S_LEN   2048
#define DMODEL  1024
#define NHEAD   16
#define DKH     64          // head dim
#define GM      8192        // BATCH*S_LEN
#define GN      1024
#define GK      1024
#define BM      128
#define BN      128
#define BK      32
#define KTILES  (GK / BK)   // 32

typedef unsigned short u16;
typedef unsigned int   u32;
typedef __attribute__((ext_vector_type(8))) short  short8;  // MFMA a/b frag
typedef __attribute__((ext_vector_type(4))) float  f32x4;

// round-to-nearest-even fp32 -> bf16 (raw bits)
__device__ __forceinline__ u16 f2bf(float f) {
    u32 u = __builtin_bit_cast(u32, f);
    u32 r = (u + 0x7fffu + ((u >> 16) & 1u)) >> 16;
    return (u16)r;
}

// async global->LDS, 16B per lane. LDS dest MUST be wave-uniform (HW adds lane*16).
__device__ __forceinline__ void gload_lds16(const u16* g, u16* l) {
    __builtin_amdgcn_global_load_lds(
        (const __attribute__((address_space(1))) u32*)g,
        (__attribute__((address_space(3))) u32*)l,
        16, 0, 0);
}

// ---------------- cast fp32 -> bf16 ----------------
__global__ void cast_kernel(const float* __restrict__ x,  const float* __restrict__ wq,
                            const float* __restrict__ wk, const float* __restrict__ wv,
                            const float* __restrict__ wo,
                            u16* __restrict__ xb,  u16* __restrict__ wqb,
                            u16* __restrict__ wkb, u16* __restrict__ wvb,
                            u16* __restrict__ wob) {
    const int X4 = BATCH * S_LEN * DMODEL / 4;   // 2097152
    const int W4 = DMODEL * DMODEL / 4;          // 262144 = 2^18
    const int total4 = X4 + 4 * W4;
    for (int i = blockIdx.x * blockDim.x + threadIdx.x; i < total4;
         i += gridDim.x * blockDim.x) {
        const float* src; u16* dst; int off;
        if (i < X4) { src = x; dst = xb; off = i; }
        else {
            int j = i - X4;
            int sel = j >> 18;
            off = j & (W4 - 1);
            src = sel == 0 ? wq : sel == 1 ? wk : sel == 2 ? wv : wo;
            dst = sel == 0 ? wqb : sel == 1 ? wkb : sel == 2 ? wvb : wob;
        }
        float4 v = ((const float4*)src)[off];
        ushort4 o;
        o.x = f2bf(v.x); o.y = f2bf(v.y); o.z = f2bf(v.z); o.w = f2bf(v.w);
        ((ushort4*)dst)[off] = o;
    }
}

// ---------------- GEMM: C[M,N] = A[M,K] * W[N,K]^T ----------------
// (unchanged from validated R3 kernel)
template<int MODE>
__global__ __launch_bounds__(256) void gemm_bt(const u16* __restrict__ A,
                                               const u16* __restrict__ W,
                                               void* __restrict__ outp,
                                               const float* __restrict__ bias) {
    __shared__ __align__(16) u16 As[2][BM * BK];
    __shared__ __align__(16) u16 Ws[2][BN * BK];

    const int tid  = threadIdx.x;
    const int lane = tid & 63;
    const int wr   = (tid >> 6) >> 1;
    const int wc   = (tid >> 6) & 1;
    const int m0   = blockIdx.x * BM;
    const int n0   = blockIdx.y * BN;

    f32x4 acc[4][4] = {};

    auto stage = [&](int buf, int kt) {
        const int k0 = kt * BK;
#pragma unroll
        for (int j = 0; j < 2; ++j) {
            int c = j * 256 + tid;
            int wu = j * 256 + (tid & 192);
            int row = c >> 2, slot = c & 3;
            int sg = slot ^ ((row >> 1) & 3);
            gload_lds16(A + (size_t)(m0 + row) * GK + k0 + sg * 8, &As[buf][wu * 8]);
        }
#pragma unroll
        for (int j = 0; j < 2; ++j) {
            int c = j * 256 + tid;
            int wu = j * 256 + (tid & 192);
            int row = c >> 2, slot = c & 3;
            int sg = slot ^ ((row >> 1) & 3);
            gload_lds16(W + (size_t)(n0 + row) * GK + k0 + sg * 8, &Ws[buf][wu * 8]);
        }
    };

    stage(0, 0);
    __syncthreads();

    for (int kt = 0; kt < KTILES; ++kt) {
        if (kt + 1 < KTILES) stage((kt + 1) & 1, kt + 1);

        const u16* ab = As[kt & 1];
        const u16* wb = Ws[kt & 1];
        const int ls = lane >> 4;
        short8 af[4], wf[4];
#pragma unroll
        for (int mi = 0; mi < 4; ++mi) {
            int row = wr * 64 + mi * 16 + (lane & 15);
            int ps = ls ^ ((row >> 1) & 3);
            af[mi] = *(const short8*)(ab + row * BK + ps * 8);
        }
#pragma unroll
        for (int ni = 0; ni < 4; ++ni) {
            int row = wc * 64 + ni * 16 + (lane & 15);
            int ps = ls ^ ((row >> 1) & 3);
            wf[ni] = *(const short8*)(wb + row * BK + ps * 8);
        }
#pragma unroll
        for (int mi = 0; mi < 4; ++mi)
#pragma unroll
            for (int ni = 0; ni < 4; ++ni)
                acc[mi][ni] = __builtin_amdgcn_mfma_f32_16x16x32_bf16(
                    af[mi], wf[ni], acc[mi][ni], 0, 0, 0);

        __syncthreads();
    }

#pragma unroll
    for (int mi = 0; mi < 4; ++mi) {
#pragma unroll
        for (int ni = 0; ni < 4; ++ni) {
#pragma unroll
            for (int r = 0; r < 4; ++r) {
                int m = m0 + wr * 64 + mi * 16 + (lane >> 4) * 4 + r;
                int n = n0 + wc * 64 + ni * 16 + (lane & 15);
                float v = acc[mi][ni][r];
                if (MODE == 2) {
                    ((float*)outp)[(size_t)m * GN + n] = v + bias[n];
                } else {
                    int b = m >> 11, s = m & (S_LEN - 1);
                    int h = n >> 6,  d = n & (DKH - 1);
                    size_t idx;
                    if (MODE == 0)
                        idx = (((size_t)(b * NHEAD + h)) * S_LEN + s) * DKH + d;
                    else
                        idx = (((size_t)(b * NHEAD + h)) * DKH + d) * S_LEN + s;
                    ((u16*)outp)[idx] = f2bf(v);
                }
            }
        }
    }
}

// ---------------- flash attention (causal) v2 ----------------
// Q-tile 128/block (4 waves x 32 q-rows, 2x16-row frags), KV tiles of 64 keys,
// K/V double-buffered: STAGE(t+1) issued BEFORE compute(t), one barrier/iter
// (syncthreads drains vmcnt -> staged tile ready AND old buffer reads done).
// XCD swizzle: each XCD owns 8 consecutive bh (KV set = 4MB = its L2),
// q-tiles descending (heavy first, LPT).
__global__ __launch_bounds__(256) void attn_kernel(const u16* __restrict__ Q,
                                                   const u16* __restrict__ Kx,
                                                   const u16* __restrict__ Vt,
                                                   u16* __restrict__ O) {
    __shared__ __align__(16) u16 Ks[2][64 * 64];
    __shared__ __align__(16) u16 Vs[2][64 * 64];
    __shared__ __align__(16) u16 Ps[4][2][16 * 72];   // per-wave, per-qi P buffer

    const int tid  = threadIdx.x;
    const int lane = tid & 63;
    const int wave = tid >> 6;

    // bijective XCD-aware remap: 1024 blocks, xcd = wgid&7 owns bh in [8*xcd, 8*xcd+8)
    const int wgid = blockIdx.x + (int)gridDim.x * blockIdx.y;
    const int xcd  = wgid & 7;
    const int idx  = wgid >> 3;             // 0..127
    const int bh   = xcd * 8 + (idx & 7);   // 0..63
    const int qt   = 15 - (idx >> 3);       // heavy tiles first
    const int b    = bh >> 4;
    const int h    = bh & 15;

    const size_t base = (size_t)bh * S_LEN * DKH;
    const u16* Qb = Q  + base;
    const u16* Kb = Kx + base;
    const u16* Vb = Vt + base;              // [DK][S]

    const int q0 = qt * 128;

    // Q fragments (A operand: row = lane&15, k = (lane>>4)*8)
    short8 qf[2][2];
#pragma unroll
    for (int qi = 0; qi < 2; ++qi) {
        int qr = q0 + wave * 32 + qi * 16 + (lane & 15);
#pragma unroll
        for (int kk = 0; kk < 2; ++kk)
            qf[qi][kk] = *(const short8*)(Qb + (size_t)qr * DKH + kk * 32 + (lane >> 4) * 8);
    }

    f32x4 acc[2][4] = {};
    float mrow[2][4], lrow[2][4];
#pragma unroll
    for (int qi = 0; qi < 2; ++qi)
#pragma unroll
        for (int r = 0; r < 4; ++r) { mrow[qi][r] = -1e30f; lrow[qi][r] = 0.f; }

    auto stage = [&](int buf, int t) {
        // K tile [key 64][dk 64], V^T tile [dk 64][key 64]; rows 128B = 8x16B slots,
        // physical slot = logical ^ (row&7); linear LDS dest + pre-swizzled source.
#pragma unroll
        for (int j = 0; j < 2; ++j) {
            int c = j * 256 + tid;
            int wu = j * 256 + (tid & 192);
            int row = c >> 3, slot = c & 7;
            int sg = slot ^ (row & 7);
            gload_lds16(Kb + (size_t)(t * 64 + row) * DKH + sg * 8, &Ks[buf][wu * 8]);
        }
#pragma unroll
        for (int j = 0; j < 2; ++j) {
            int c = j * 256 + tid;
            int wu = j * 256 + (tid & 192);
            int row = c >> 3, slot = c & 7;
            int sg = slot ^ (row & 7);
            gload_lds16(Vb + (size_t)row * S_LEN + t * 64 + sg * 8, &Vs[buf][wu * 8]);
        }
    };

    const int nt = 2 * (qt + 1);
    const int qmax_w = q0 + wave * 32 + 31;   // this wave's max q-row

    stage(0, 0);
    __syncthreads();      // drains vmcnt: tile 0 ready

    for (int t = 0; t < nt; ++t) {
        const int cur = t & 1;
        if (t + 1 < nt) stage(cur ^ 1, t + 1);   // prefetch BEFORE compute

        if (t * 64 <= qmax_w) {                  // skip fully-masked tiles (wave-uniform)
            const u16* kb = Ks[cur];
            const u16* vb = Vs[cur];
#pragma unroll
            for (int qi = 0; qi < 2; ++qi) {
                // ---- QK^T ----
                f32x4 sc[4] = {};
#pragma unroll
                for (int ni = 0; ni < 4; ++ni) {
#pragma unroll
                    for (int kk = 0; kk < 2; ++kk) {
                        int row = ni * 16 + (lane & 15);
                        int ps = (kk * 4 + (lane >> 4)) ^ (row & 7);
                        short8 kf = *(const short8*)(kb + row * 64 + ps * 8);
                        sc[ni] = __builtin_amdgcn_mfma_f32_16x16x32_bf16(
                            qf[qi][kk], kf, sc[ni], 0, 0, 0);
                    }
                }

                // ---- scale + causal mask ----
                const bool diag = (t * 64 + 63) > (q0 + wave * 32 + qi * 16);
#pragma unroll
                for (int ni = 0; ni < 4; ++ni) {
#pragma unroll
                    for (int r = 0; r < 4; ++r) {
                        float s = sc[ni][r] * 0.125f;
                        if (diag) {
                            int key = t * 64 + ni * 16 + (lane & 15);
                            int qr  = q0 + wave * 32 + qi * 16 + (lane >> 4) * 4 + r;
                            if (key > qr) s = -1e30f;
                        }
                        sc[ni][r] = s;
                    }
                }

                // ---- online softmax (reduce across 16-lane groups) ----
                u16* pw = Ps[wave][qi];
                float alpha[4];
#pragma unroll
                for (int r = 0; r < 4; ++r) {
                    float tm = fmaxf(fmaxf(sc[0][r], sc[1][r]), fmaxf(sc[2][r], sc[3][r]));
#pragma unroll
                    for (int off = 1; off < 16; off <<= 1)
                        tm = fmaxf(tm, __shfl_xor(tm, off));
                    float mn = fmaxf(mrow[qi][r], tm);
                    alpha[r] = __expf(mrow[qi][r] - mn);
                    mrow[qi][r] = mn;
                    float rs = 0.f;
#pragma unroll
                    for (int ni = 0; ni < 4; ++ni) {
                        float p = __expf(sc[ni][r] - mn);
                        pw[((lane >> 4) * 4 + r) * 72 + ni * 16 + (lane & 15)] = f2bf(p);
                        rs += p;
                    }
#pragma unroll
                    for (int off = 1; off < 16; off <<= 1)
                        rs += __shfl_xor(rs, off);
                    lrow[qi][r] = lrow[qi][r] * alpha[r] + rs;
                }
#pragma unroll
                for (int di = 0; di < 4; ++di)
#pragma unroll
                    for (int r = 0; r < 4; ++r)
                        acc[qi][di][r] *= alpha[r];

                // ---- PV ----
#pragma unroll
                for (int kk = 0; kk < 2; ++kk) {
                    short8 pa = *(const short8*)(pw + (lane & 15) * 72 + kk * 32 + (lane >> 4) * 8);
#pragma unroll
                    for (int di = 0; di < 4; ++di) {
                        int row = di * 16 + (lane & 15);
                        int ps = (kk * 4 + (lane >> 4)) ^ (row & 7);
                        short8 vf = *(const short8*)(vb + row * 64 + ps * 8);
                        acc[qi][di] = __builtin_amdgcn_mfma_f32_16x16x32_bf16(
                            pa, vf, acc[qi][di], 0, 0, 0);
                    }
                }
            }
        }
        __syncthreads();   // staged t+1 ready; all waves done with buf cur^1
    }

    // ---- epilogue: O[b][s][h*64+dk] ----
#pragma unroll
    for (int qi = 0; qi < 2; ++qi)
#pragma unroll
        for (int di = 0; di < 4; ++di)
#pragma unroll
            for (int r = 0; r < 4; ++r) {
                int s = q0 + wave * 32 + qi * 16 + (lane >> 4) * 4 + r;
                int d = di * 16 + (lane & 15);
                float v = acc[qi][di][r] / lrow[qi][r];
                O[((size_t)b * S_LEN + s) * DMODEL + h * 64 + d] = f2bf(v);
            }
}

// ---------------- launcher ----------------
extern "C" void kernel_launch(void* const* d_in, const int* in_sizes, int n_in,
                              void* d_out, int out_size, void* d_ws, size_t ws_size,
                              hipStream_t stream) {
    const float* x  = (const float*)d_in[0];
    const float* wq = (const float*)d_in[1];
    const float* wk = (const float*)d_in[2];
    const float* wv = (const float*)d_in[3];
    const float* wo = (const float*)d_in[4];
    const float* bo = (const float*)d_in[5];

    const size_t XB  = (size_t)BATCH * S_LEN * DMODEL * 2;  // 16 MB
    const size_t WB  = (size_t)DMODEL * DMODEL * 2;         // 2 MB

    char* p = (char*)d_ws;
    u16* xb  = (u16*)p; p += XB;   // reused as attention output Od (x dead after V GEMM)
    u16* wqb = (u16*)p; p += WB;
    u16* wkb = (u16*)p; p += WB;
    u16* wvb = (u16*)p; p += WB;
    u16* wob = (u16*)p; p += WB;
    u16* Qd  = (u16*)p; p += XB;
    u16* Kd  = (u16*)p; p += XB;
    u16* Vtd = (u16*)p; p += XB;
    u16* Od  = xb;
    // total workspace: 4*16MB + 4*2MB = 72 MB

    cast_kernel<<<2048, 256, 0, stream>>>(x, wq, wk, wv, wo, xb, wqb, wkb, wvb, wob);

    dim3 gg(GM / BM, GN / BN);   // 64 x 8
    gemm_bt<0><<<gg, 256, 0, stream>>>(xb, wqb, Qd,  nullptr);
    gemm_bt<0><<<gg, 256, 0, stream>>>(xb, wkb, Kd,  nullptr);
    gemm_bt<1><<<gg, 256, 0, stream>>>(xb, wvb, Vtd, nullptr);

    attn_kernel<<<dim3(S_LEN / 128, BATCH * NHEAD), 256, 0, stream>>>(Qd, Kd, Vtd, Od);

    gemm_bt<2><<<gg, 256, 0, stream>>>(Od, wob, d_out, bo);
}

// Round 7
// 314.566 us; speedup vs baseline: 1.3742x; 1.0858x over previous
//
#include <hip/hip_runtime.h>
#include <hip/hip_bf16.h>

// ---------------- problem constants ----------------
#define BATCH   4
#define S_LEN   2048
#define DMODEL  1024
#define NHEAD   16
#define DKH     64
#define GM      8192        // BATCH*S_LEN
#define GK      1024
#define BM      128
#define BN      128
#define BK      32
#define KTILES  (GK / BK)   // 32

typedef unsigned short u16;
typedef unsigned int   u32;
typedef __attribute__((ext_vector_type(8)))  short short8;   // 8 bf16 (MFMA a/b)
typedef __attribute__((ext_vector_type(4)))  float f32x4;
typedef __attribute__((ext_vector_type(16))) float f32x16;
typedef __attribute__((ext_vector_type(4)))  u32   u32x4;

__device__ __forceinline__ u16 f2bf(float f) {
    __hip_bfloat16 h = __float2bfloat16(f);      // RNE, compiler packs to cvt_pk
    return __builtin_bit_cast(u16, h);
}

// packed fp32 pair -> bf16x2 (lo in low half)
__device__ __forceinline__ u32 cvt_pk_bf16(float lo, float hi) {
    u32 r;
    asm("v_cvt_pk_bf16_f32 %0, %1, %2" : "=v"(r) : "v"(lo), "v"(hi));
    return r;
}

// async global->LDS, 16B per lane. LDS dest wave-uniform (HW adds lane*16).
__device__ __forceinline__ void gload_lds16(const u16* g, u16* l) {
    __builtin_amdgcn_global_load_lds(
        (const __attribute__((address_space(1))) u32*)g,
        (__attribute__((address_space(3))) u32*)l,
        16, 0, 0);
}

// ---------------- cast fp32 -> bf16 (weights: wq|wk|wv contiguous) ----------------
__global__ void cast_kernel(const float* __restrict__ x,  const float* __restrict__ wq,
                            const float* __restrict__ wk, const float* __restrict__ wv,
                            const float* __restrict__ wo,
                            u16* __restrict__ xb, u16* __restrict__ wqkv, u16* __restrict__ wob) {
    const int X4 = BATCH * S_LEN * DMODEL / 4;
    const int W4 = DMODEL * DMODEL / 4;          // 2^18
    const int total4 = X4 + 4 * W4;
    for (int i = blockIdx.x * blockDim.x + threadIdx.x; i < total4;
         i += gridDim.x * blockDim.x) {
        const float* src; u16* dst; int off;
        if (i < X4) { src = x; dst = xb; off = i; }
        else {
            int j = i - X4;
            int sel = j >> 18;
            off = j & (W4 - 1);
            src = sel == 0 ? wq : sel == 1 ? wk : sel == 2 ? wv : wo;
            dst = sel < 3 ? wqkv + (size_t)sel * DMODEL * DMODEL : wob;
        }
        float4 v = ((const float4*)src)[off];
        ushort4 o;
        o.x = f2bf(v.x); o.y = f2bf(v.y); o.z = f2bf(v.z); o.w = f2bf(v.w);
        ((ushort4*)dst)[off] = o;
    }
}

// ---------------- fused QKV GEMM: [8192,1024] x [3072,1024]^T ----------------
// n0 block-uniform selects Q / K (bf16 [B,H,S,DK]) or V^T (bf16 [B,H,DK,S]).
__global__ __launch_bounds__(256) void gemm_qkv(const u16* __restrict__ A,
                                                const u16* __restrict__ W3,
                                                u16* __restrict__ Qd,
                                                u16* __restrict__ Kd,
                                                u16* __restrict__ Vtd) {
    __shared__ __align__(16) u16 As[2][BM * BK];
    __shared__ __align__(16) u16 Ws[2][BN * BK];

    const int tid  = threadIdx.x;
    const int lane = tid & 63;
    const int wr   = (tid >> 6) >> 1;
    const int wc   = (tid >> 6) & 1;
    const int m0   = blockIdx.x * BM;
    const int n0   = blockIdx.y * BN;   // 0..2944

    f32x4 acc[4][4] = {};

    auto stage = [&](int buf, int kt) {
        const int k0 = kt * BK;
#pragma unroll
        for (int j = 0; j < 2; ++j) {
            int c = j * 256 + tid, wu = j * 256 + (tid & 192);
            int row = c >> 2, slot = c & 3;
            int sg = slot ^ ((row >> 1) & 3);
            gload_lds16(A + (size_t)(m0 + row) * GK + k0 + sg * 8, &As[buf][wu * 8]);
        }
#pragma unroll
        for (int j = 0; j < 2; ++j) {
            int c = j * 256 + tid, wu = j * 256 + (tid & 192);
            int row = c >> 2, slot = c & 3;
            int sg = slot ^ ((row >> 1) & 3);
            gload_lds16(W3 + (size_t)(n0 + row) * GK + k0 + sg * 8, &Ws[buf][wu * 8]);
        }
    };

    stage(0, 0);
    __syncthreads();

    for (int kt = 0; kt < KTILES; ++kt) {
        if (kt + 1 < KTILES) stage((kt + 1) & 1, kt + 1);
        const u16* ab = As[kt & 1];
        const u16* wb = Ws[kt & 1];
        const int ls = lane >> 4;
        short8 af[4], wf[4];
#pragma unroll
        for (int mi = 0; mi < 4; ++mi) {
            int row = wr * 64 + mi * 16 + (lane & 15);
            int ps = ls ^ ((row >> 1) & 3);
            af[mi] = *(const short8*)(ab + row * BK + ps * 8);
        }
#pragma unroll
        for (int ni = 0; ni < 4; ++ni) {
            int row = wc * 64 + ni * 16 + (lane & 15);
            int ps = ls ^ ((row >> 1) & 3);
            wf[ni] = *(const short8*)(wb + row * BK + ps * 8);
        }
#pragma unroll
        for (int mi = 0; mi < 4; ++mi)
#pragma unroll
            for (int ni = 0; ni < 4; ++ni)
                acc[mi][ni] = __builtin_amdgcn_mfma_f32_16x16x32_bf16(
                    af[mi], wf[ni], acc[mi][ni], 0, 0, 0);
        __syncthreads();
    }

    const int sel = n0 >> 10;   // 0:Q 1:K 2:V  (block-uniform, BN | 1024)
#pragma unroll
    for (int mi = 0; mi < 4; ++mi)
#pragma unroll
        for (int ni = 0; ni < 4; ++ni)
#pragma unroll
            for (int r = 0; r < 4; ++r) {
                int m = m0 + wr * 64 + mi * 16 + (lane >> 4) * 4 + r;
                int n = n0 + wc * 64 + ni * 16 + (lane & 15);
                int nl = n & 1023;
                int b = m >> 11, s = m & (S_LEN - 1);
                int h = nl >> 6, d = nl & (DKH - 1);
                u16 v = f2bf(acc[mi][ni][r]);
                if (sel == 0)
                    Qd[(((size_t)(b * NHEAD + h)) * S_LEN + s) * DKH + d] = v;
                else if (sel == 1)
                    Kd[(((size_t)(b * NHEAD + h)) * S_LEN + s) * DKH + d] = v;
                else
                    Vtd[(((size_t)(b * NHEAD + h)) * DKH + d) * S_LEN + s] = v;
            }
}

// ---------------- output projection GEMM (+bias, fp32 out) ----------------
__global__ __launch_bounds__(256) void gemm_out(const u16* __restrict__ A,
                                                const u16* __restrict__ W,
                                                float* __restrict__ outp,
                                                const float* __restrict__ bias) {
    __shared__ __align__(16) u16 As[2][BM * BK];
    __shared__ __align__(16) u16 Ws[2][BN * BK];

    const int tid  = threadIdx.x;
    const int lane = tid & 63;
    const int wr   = (tid >> 6) >> 1;
    const int wc   = (tid >> 6) & 1;
    const int m0   = blockIdx.x * BM;
    const int n0   = blockIdx.y * BN;

    f32x4 acc[4][4] = {};

    auto stage = [&](int buf, int kt) {
        const int k0 = kt * BK;
#pragma unroll
        for (int j = 0; j < 2; ++j) {
            int c = j * 256 + tid, wu = j * 256 + (tid & 192);
            int row = c >> 2, slot = c & 3;
            int sg = slot ^ ((row >> 1) & 3);
            gload_lds16(A + (size_t)(m0 + row) * GK + k0 + sg * 8, &As[buf][wu * 8]);
        }
#pragma unroll
        for (int j = 0; j < 2; ++j) {
            int c = j * 256 + tid, wu = j * 256 + (tid & 192);
            int row = c >> 2, slot = c & 3;
            int sg = slot ^ ((row >> 1) & 3);
            gload_lds16(W + (size_t)(n0 + row) * GK + k0 + sg * 8, &Ws[buf][wu * 8]);
        }
    };

    stage(0, 0);
    __syncthreads();

    for (int kt = 0; kt < KTILES; ++kt) {
        if (kt + 1 < KTILES) stage((kt + 1) & 1, kt + 1);
        const u16* ab = As[kt & 1];
        const u16* wb = Ws[kt & 1];
        const int ls = lane >> 4;
        short8 af[4], wf[4];
#pragma unroll
        for (int mi = 0; mi < 4; ++mi) {
            int row = wr * 64 + mi * 16 + (lane & 15);
            int ps = ls ^ ((row >> 1) & 3);
            af[mi] = *(const short8*)(ab + row * BK + ps * 8);
        }
#pragma unroll
        for (int ni = 0; ni < 4; ++ni) {
            int row = wc * 64 + ni * 16 + (lane & 15);
            int ps = ls ^ ((row >> 1) & 3);
            wf[ni] = *(const short8*)(wb + row * BK + ps * 8);
        }
#pragma unroll
        for (int mi = 0; mi < 4; ++mi)
#pragma unroll
            for (int ni = 0; ni < 4; ++ni)
                acc[mi][ni] = __builtin_amdgcn_mfma_f32_16x16x32_bf16(
                    af[mi], wf[ni], acc[mi][ni], 0, 0, 0);
        __syncthreads();
    }

#pragma unroll
    for (int mi = 0; mi < 4; ++mi)
#pragma unroll
        for (int ni = 0; ni < 4; ++ni)
#pragma unroll
            for (int r = 0; r < 4; ++r) {
                int m = m0 + wr * 64 + mi * 16 + (lane >> 4) * 4 + r;
                int n = n0 + wc * 64 + ni * 16 + (lane & 15);
                outp[(size_t)m * DMODEL + n] = acc[mi][ni][r] + bias[n];
            }
}

// ---------------- flash attention v3: swapped 32x32 QK^T, in-register softmax ----
// 1024 blocks (16 qt x 64 bh), 256 thr (4 waves x 32 q-rows).
// S^T = mfma_32x32x16(K_frag, Q_frag): lane = one q-col (lane&31), 32 keys in-lane
//   (key = 32s + (reg&3) + 8*(reg>>2) + 4*(lane>>5)).
// Softmax: in-lane reduce + one shfl_xor(32). Rescale skipped when __all(tm<=m) (exact).
// P -> PV A-frags in registers: cvt_pk pairs + shfl_xor(32) + selects (no LDS P).
// K/V double-buffered in LDS (8x16B slots, slot^=(row&7)); stage(t+1) before compute(t).
__global__ __launch_bounds__(256) void attn_kernel(const u16* __restrict__ Q,
                                                   const u16* __restrict__ Kx,
                                                   const u16* __restrict__ Vt,
                                                   u16* __restrict__ O) {
    __shared__ __align__(16) u16 Ks[2][64 * 64];
    __shared__ __align__(16) u16 Vs[2][64 * 64];

    const int tid  = threadIdx.x;
    const int lane = tid & 63;
    const int wave = tid >> 6;
    const int hx   = lane >> 5;     // lane half
    const int ql   = lane & 31;     // q column

    // XCD-aware remap (xcd owns 8 bh = 4MB KV = its L2), heavy q-tiles first (LPT)
    const int wgid = blockIdx.x;
    const int xcd  = wgid & 7;
    const int idx  = wgid >> 3;
    const int bh   = xcd * 8 + (idx & 7);
    const int qt   = 15 - (idx >> 3);
    const int b    = bh >> 4;
    const int hh   = bh & 15;

    const size_t base = (size_t)bh * S_LEN * DKH;
    const u16* Qb = Q  + base;
    const u16* Kb = Kx + base;
    const u16* Vb = Vt + base;      // [DK][S]

    const int q0 = qt * 128;
    const int qw = q0 + wave * 32;
    const int qrow = qw + ql;       // this lane's q (softmax state owner)

    // Q as MFMA B-operand: col=lane&31=q, k = 16c + 8*hx + j
    short8 qf[4];
#pragma unroll
    for (int c = 0; c < 4; ++c)
        qf[c] = *(const short8*)(Qb + (size_t)qrow * DKH + c * 16 + hx * 8);

    f32x16 acc[2] = {};             // O[q_local][dk = 32n + ql]
    float m = -1e30f, l = 0.f;

    auto stage = [&](int buf, int t) {
#pragma unroll
        for (int j = 0; j < 2; ++j) {
            int c = j * 256 + tid, wu = j * 256 + (tid & 192);
            int row = c >> 3, slot = c & 7;
            int sg = slot ^ (row & 7);
            gload_lds16(Kb + (size_t)(t * 64 + row) * DKH + sg * 8, &Ks[buf][wu * 8]);
        }
#pragma unroll
        for (int j = 0; j < 2; ++j) {
            int c = j * 256 + tid, wu = j * 256 + (tid & 192);
            int row = c >> 3, slot = c & 7;
            int sg = slot ^ (row & 7);
            gload_lds16(Vb + (size_t)row * S_LEN + t * 64 + sg * 8, &Vs[buf][wu * 8]);
        }
    };

    const int nt = 2 * (qt + 1);
    const int qmax_w = qw + 31;
    const float SC2 = 0.18033688011f;   // 0.125 * log2(e)

    stage(0, 0);
    __syncthreads();

    for (int t = 0; t < nt; ++t) {
        const int cur = t & 1;
        if (t + 1 < nt) stage(cur ^ 1, t + 1);

        if (t * 64 <= qmax_w) {
            const u16* kb = Ks[cur];
            const u16* vb = Vs[cur];
            const int smax = (t * 64 + 32 <= qmax_w) ? 2 : 1;

            // ---- QK^T swapped: sc[s] = S^T[key 32s..][q] ----
            f32x16 sc[2];
#pragma unroll
            for (int s = 0; s < 2; ++s) if (s < smax) {
                f32x16 z = {};
#pragma unroll
                for (int c = 0; c < 4; ++c) {
                    int row = s * 32 + ql;              // key row in LDS
                    int ps = (2 * c + hx) ^ (row & 7);
                    short8 kf = *(const short8*)(kb + row * 64 + ps * 8);
                    z = __builtin_amdgcn_mfma_f32_32x32x16_bf16(kf, qf[c], z, 0, 0, 0);
                }
                sc[s] = z;
            }

            // ---- scale + causal mask + row max ----
            const bool needmask = (t * 64 + 63) > qw;
            const int kbase = t * 64 + hx * 4;
            float tm = -1e30f;
#pragma unroll
            for (int s = 0; s < 2; ++s) if (s < smax) {
#pragma unroll
                for (int r = 0; r < 16; ++r) {
                    float v = sc[s][r] * SC2;
                    if (needmask) {
                        int key = kbase + 32 * s + (r & 3) + 8 * (r >> 2);
                        if (key > qrow) v = -1e30f;
                    }
                    sc[s][r] = v;
                    tm = fmaxf(tm, v);
                }
            }
            tm = fmaxf(tm, __shfl_xor(tm, 32));

            // ---- rescale (exact skip when max unchanged for ALL rows) ----
            if (!__all(tm <= m)) {
                float mn = fmaxf(m, tm);
                float alpha = exp2f(m - mn);
                m = mn; l *= alpha;
#pragma unroll
                for (int r = 0; r < 16; ++r) {
                    int qloc = (r & 3) + 8 * (r >> 2) + 4 * hx;
                    float ar = __shfl(alpha, qloc);
                    acc[0][r] *= ar;
                    acc[1][r] *= ar;
                }
            }

            // ---- exp2 + row sum ----
            float rs = 0.f;
#pragma unroll
            for (int s = 0; s < 2; ++s) if (s < smax) {
#pragma unroll
                for (int r = 0; r < 16; ++r) {
                    float p = exp2f(sc[s][r] - m);
                    sc[s][r] = p;
                    rs += p;
                }
            }
            rs += __shfl_xor(rs, 32);
            l += rs;

            // ---- pack P to bf16 pairs: pk[s][blk][h2] = keys 32s+8blk+4hx+2h2+{0,1} ----
            u32 pk[2][4][2];
#pragma unroll
            for (int s = 0; s < 2; ++s) if (s < smax) {
#pragma unroll
                for (int blk = 0; blk < 4; ++blk) {
                    pk[s][blk][0] = cvt_pk_bf16(sc[s][4 * blk],     sc[s][4 * blk + 1]);
                    pk[s][blk][1] = cvt_pk_bf16(sc[s][4 * blk + 2], sc[s][4 * blk + 3]);
                }
            }

            // ---- PV per key-16-chunk: build A-frag (keys 16t4+8hx+j) via xor32 ----
#pragma unroll
            for (int t4 = 0; t4 < 4; ++t4) if (t4 < 2 * smax) {
                int s  = t4 >> 1;
                int bb = 2 * (t4 & 1);
                u32 own0 = hx ? pk[s][bb + 1][0] : pk[s][bb][0];
                u32 own1 = hx ? pk[s][bb + 1][1] : pk[s][bb][1];
                u32 pay0 = hx ? pk[s][bb][0]     : pk[s][bb + 1][0];
                u32 pay1 = hx ? pk[s][bb][1]     : pk[s][bb + 1][1];
                u32 rcv0 = __shfl_xor(pay0, 32);
                u32 rcv1 = __shfl_xor(pay1, 32);
                u32x4 aw;
                aw.x = hx ? rcv0 : own0;
                aw.y = hx ? rcv1 : own1;
                aw.z = hx ? own0 : rcv0;
                aw.w = hx ? own1 : rcv1;
                short8 pa = __builtin_bit_cast(short8, aw);
#pragma unroll
                for (int n = 0; n < 2; ++n) {
                    int row = 32 * n + ql;              // dk row in V^T LDS
                    int ps = (2 * t4 + hx) ^ (row & 7);
                    short8 vf = *(const short8*)(vb + row * 64 + ps * 8);
                    acc[n] = __builtin_amdgcn_mfma_f32_32x32x16_bf16(pa, vf, acc[n], 0, 0, 0);
                }
            }
        }
        __syncthreads();
    }

    // ---- epilogue ----
    float inv = 1.0f / l;
#pragma unroll
    for (int r = 0; r < 16; ++r) {
        int qloc = (r & 3) + 8 * (r >> 2) + 4 * hx;
        float li = __shfl(inv, qloc);
        size_t obase = ((size_t)b * S_LEN + (qw + qloc)) * DMODEL + hh * 64;
        O[obase + ql]      = f2bf(acc[0][r] * li);
        O[obase + 32 + ql] = f2bf(acc[1][r] * li);
    }
}

// ---------------- launcher ----------------
extern "C" void kernel_launch(void* const* d_in, const int* in_sizes, int n_in,
                              void* d_out, int out_size, void* d_ws, size_t ws_size,
                              hipStream_t stream) {
    const float* x  = (const float*)d_in[0];
    const float* wq = (const float*)d_in[1];
    const float* wk = (const float*)d_in[2];
    const float* wv = (const float*)d_in[3];
    const float* wo = (const float*)d_in[4];
    const float* bo = (const float*)d_in[5];

    const size_t XB = (size_t)BATCH * S_LEN * DMODEL * 2;  // 16 MB
    const size_t WB = (size_t)DMODEL * DMODEL * 2;         // 2 MB

    char* p = (char*)d_ws;
    u16* xb   = (u16*)p; p += XB;      // reused as attention output Od
    u16* wqkv = (u16*)p; p += 3 * WB;  // wq|wk|wv rows 0..3071
    u16* wob  = (u16*)p; p += WB;
    u16* Qd   = (u16*)p; p += XB;
    u16* Kd   = (u16*)p; p += XB;
    u16* Vtd  = (u16*)p; p += XB;
    u16* Od   = xb;
    // total workspace: 4*16MB + 4*2MB = 72 MB

    cast_kernel<<<2048, 256, 0, stream>>>(x, wq, wk, wv, wo, xb, wqkv, wob);

    gemm_qkv<<<dim3(GM / BM, 3072 / BN), 256, 0, stream>>>(xb, wqkv, Qd, Kd, Vtd);

    attn_kernel<<<1024, 256, 0, stream>>>(Qd, Kd, Vtd, Od);

    gemm_out<<<dim3(GM / BM, DMODEL / BN), 256, 0, stream>>>(Od, wob, (float*)d_out, bo);
}

// Round 11
// 292.563 us; speedup vs baseline: 1.4776x; 1.0752x over previous
//
#include <hip/hip_runtime.h>
#include <hip/hip_bf16.h>

// ---------------- problem constants ----------------
#define BATCH   4
#define S_LEN   2048
#define DMODEL  1024
#define NHEAD   16
#define DKH     64
#define GM      8192        // BATCH*S_LEN
#define GK      1024
#define BM      128
#define BN      128
#define BK      32
#define KTILES  (GK / BK)   // 32

typedef unsigned short u16;
typedef unsigned int   u32;
typedef __attribute__((ext_vector_type(8)))  short short8;   // 8 bf16 (MFMA a/b)
typedef __attribute__((ext_vector_type(4)))  float f32x4;
typedef __attribute__((ext_vector_type(16))) float f32x16;
typedef __attribute__((ext_vector_type(4)))  u32   u32x4;

#define QSCALE 0.18033688011f   // 0.125 * log2(e), folded into Q at projection

__device__ __forceinline__ u16 f2bf(float f) {
    __hip_bfloat16 h = __float2bfloat16(f);
    return __builtin_bit_cast(u16, h);
}

// packed fp32 pair -> bf16x2 (lo in low half)  [verified in R7]
__device__ __forceinline__ u32 cvt_pk_bf16(float lo, float hi) {
    u32 r;
    asm("v_cvt_pk_bf16_f32 %0, %1, %2" : "=v"(r) : "v"(lo), "v"(hi));
    return r;
}

// async global->LDS, 16B per lane. LDS dest wave-uniform (HW adds lane*16).
__device__ __forceinline__ void gload_lds16(const u16* g, u16* l) {
    __builtin_amdgcn_global_load_lds(
        (const __attribute__((address_space(1))) u32*)g,
        (__attribute__((address_space(3))) u32*)l,
        16, 0, 0);
}

// ---------------- cast fp32 -> bf16 (weights: wq|wk|wv contiguous) ----------------
__global__ void cast_kernel(const float* __restrict__ x,  const float* __restrict__ wq,
                            const float* __restrict__ wk, const float* __restrict__ wv,
                            const float* __restrict__ wo,
                            u16* __restrict__ xb, u16* __restrict__ wqkv, u16* __restrict__ wob) {
    const int X4 = BATCH * S_LEN * DMODEL / 4;
    const int W4 = DMODEL * DMODEL / 4;          // 2^18
    const int total4 = X4 + 4 * W4;
    for (int i = blockIdx.x * blockDim.x + threadIdx.x; i < total4;
         i += gridDim.x * blockDim.x) {
        const float* src; u16* dst; int off;
        if (i < X4) { src = x; dst = xb; off = i; }
        else {
            int j = i - X4;
            int sel = j >> 18;
            off = j & (W4 - 1);
            src = sel == 0 ? wq : sel == 1 ? wk : sel == 2 ? wv : wo;
            dst = sel < 3 ? wqkv + (size_t)sel * DMODEL * DMODEL : wob;
        }
        float4 v = ((const float4*)src)[off];
        ushort4 o;
        o.x = f2bf(v.x); o.y = f2bf(v.y); o.z = f2bf(v.z); o.w = f2bf(v.w);
        ((ushort4*)dst)[off] = o;
    }
}

// ---------------- fused QKV GEMM: [8192,1024] x [3072,1024]^T ----------------
// sel (block-uniform) 0: Q bf16 [B,H,S,DK] PRE-SCALED by QSCALE; 1: K bf16 [B,H,S,DK];
// 2: V^T bf16 [B,H,DK,S] via LDS-transpose epilogue (coalesced 16B stores).
__global__ __launch_bounds__(256) void gemm_qkv(const u16* __restrict__ A,
                                                const u16* __restrict__ W3,
                                                u16* __restrict__ Qd,
                                                u16* __restrict__ Kd,
                                                u16* __restrict__ Vtd) {
    __shared__ __align__(16) u16 SMEM[16384];    // 32 KB: As[2][4096] | Ws[2][4096]
    u16* As = SMEM;
    u16* Ws = SMEM + 8192;

    const int tid  = threadIdx.x;
    const int lane = tid & 63;
    const int wr   = (tid >> 6) >> 1;
    const int wc   = (tid >> 6) & 1;
    const int m0   = blockIdx.x * BM;
    const int n0   = blockIdx.y * BN;   // 0..2944

    f32x4 acc[4][4] = {};

    auto stage = [&](int buf, int kt) {
        const int k0 = kt * BK;
#pragma unroll
        for (int j = 0; j < 2; ++j) {
            int c = j * 256 + tid, wu = j * 256 + (tid & 192);
            int row = c >> 2, slot = c & 3;
            int sg = slot ^ ((row >> 1) & 3);
            gload_lds16(A + (size_t)(m0 + row) * GK + k0 + sg * 8, As + buf * 4096 + wu * 8);
        }
#pragma unroll
        for (int j = 0; j < 2; ++j) {
            int c = j * 256 + tid, wu = j * 256 + (tid & 192);
            int row = c >> 2, slot = c & 3;
            int sg = slot ^ ((row >> 1) & 3);
            gload_lds16(W3 + (size_t)(n0 + row) * GK + k0 + sg * 8, Ws + buf * 4096 + wu * 8);
        }
    };

    stage(0, 0);
    __syncthreads();

    for (int kt = 0; kt < KTILES; ++kt) {
        if (kt + 1 < KTILES) stage((kt + 1) & 1, kt + 1);
        const u16* ab = As + (kt & 1) * 4096;
        const u16* wb = Ws + (kt & 1) * 4096;
        const int ls = lane >> 4;
        short8 af[4], wf[4];
#pragma unroll
        for (int mi = 0; mi < 4; ++mi) {
            int row = wr * 64 + mi * 16 + (lane & 15);
            int ps = ls ^ ((row >> 1) & 3);
            af[mi] = *(const short8*)(ab + row * BK + ps * 8);
        }
#pragma unroll
        for (int ni = 0; ni < 4; ++ni) {
            int row = wc * 64 + ni * 16 + (lane & 15);
            int ps = ls ^ ((row >> 1) & 3);
            wf[ni] = *(const short8*)(wb + row * BK + ps * 8);
        }
#pragma unroll
        for (int mi = 0; mi < 4; ++mi)
#pragma unroll
            for (int ni = 0; ni < 4; ++ni)
                acc[mi][ni] = __builtin_amdgcn_mfma_f32_16x16x32_bf16(
                    af[mi], wf[ni], acc[mi][ni], 0, 0, 0);
        __syncthreads();
    }

    const int sel = n0 >> 10;   // 0:Q 1:K 2:V  (block-uniform)
    if (sel == 2) {
        // ---- transpose through SMEM (safe after final barrier), XOR-swizzled slots ----
#pragma unroll
        for (int mi = 0; mi < 4; ++mi)
#pragma unroll
            for (int ni = 0; ni < 4; ++ni)
#pragma unroll
                for (int r = 0; r < 4; ++r) {
                    int ml = wr * 64 + mi * 16 + (lane >> 4) * 4 + r;
                    int nl = wc * 64 + ni * 16 + (lane & 15);
                    SMEM[nl * 128 + (((ml >> 3) ^ (nl & 7)) << 3) + (ml & 7)] =
                        f2bf(acc[mi][ni][r]);
                }
        __syncthreads();
        const int row = tid >> 1;            // dk-row in tile: 0..127
        const int ch0 = (tid & 1) * 8;       // m-chunk half
        const int nl2 = (n0 & 1023) + row;
        const int h = nl2 >> 6, d = nl2 & 63;
        const int bglob = m0 >> 11, s0 = m0 & 2047;
        const size_t vrow = (((size_t)(bglob * NHEAD + h)) * DKH + d) * S_LEN + s0;
#pragma unroll
        for (int i = 0; i < 8; ++i) {
            int c = ch0 + i;
            short8 v = *(const short8*)(SMEM + row * 128 + ((c ^ (row & 7)) << 3));
            *(short8*)(Vtd + vrow + c * 8) = v;
        }
    } else {
        const float qs = (sel == 0) ? QSCALE : 1.0f;
        u16* dst = (sel == 0) ? Qd : Kd;
#pragma unroll
        for (int mi = 0; mi < 4; ++mi)
#pragma unroll
            for (int ni = 0; ni < 4; ++ni)
#pragma unroll
                for (int r = 0; r < 4; ++r) {
                    int m = m0 + wr * 64 + mi * 16 + (lane >> 4) * 4 + r;
                    int n = n0 + wc * 64 + ni * 16 + (lane & 15);
                    int nl = n & 1023;
                    int b = m >> 11, s = m & (S_LEN - 1);
                    int h = nl >> 6, d = nl & (DKH - 1);
                    dst[(((size_t)(b * NHEAD + h)) * S_LEN + s) * DKH + d] =
                        f2bf(acc[mi][ni][r] * qs);
                }
    }
}

// ---------------- output projection GEMM (+bias, fp32 out) ----------------
__global__ __launch_bounds__(256) void gemm_out(const u16* __restrict__ A,
                                                const u16* __restrict__ W,
                                                float* __restrict__ outp,
                                                const float* __restrict__ bias) {
    __shared__ __align__(16) u16 As[2][BM * BK];
    __shared__ __align__(16) u16 Ws[2][BN * BK];

    const int tid  = threadIdx.x;
    const int lane = tid & 63;
    const int wr   = (tid >> 6) >> 1;
    const int wc   = (tid >> 6) & 1;
    const int m0   = blockIdx.x * BM;
    const int n0   = blockIdx.y * BN;

    f32x4 acc[4][4] = {};

    auto stage = [&](int buf, int kt) {
        const int k0 = kt * BK;
#pragma unroll
        for (int j = 0; j < 2; ++j) {
            int c = j * 256 + tid, wu = j * 256 + (tid & 192);
            int row = c >> 2, slot = c & 3;
            int sg = slot ^ ((row >> 1) & 3);
            gload_lds16(A + (size_t)(m0 + row) * GK + k0 + sg * 8, &As[buf][wu * 8]);
        }
#pragma unroll
        for (int j = 0; j < 2; ++j) {
            int c = j * 256 + tid, wu = j * 256 + (tid & 192);
            int row = c >> 2, slot = c & 3;
            int sg = slot ^ ((row >> 1) & 3);
            gload_lds16(W + (size_t)(n0 + row) * GK + k0 + sg * 8, &Ws[buf][wu * 8]);
        }
    };

    stage(0, 0);
    __syncthreads();

    for (int kt = 0; kt < KTILES; ++kt) {
        if (kt + 1 < KTILES) stage((kt + 1) & 1, kt + 1);
        const u16* ab = As[kt & 1];
        const u16* wb = Ws[kt & 1];
        const int ls = lane >> 4;
        short8 af[4], wf[4];
#pragma unroll
        for (int mi = 0; mi < 4; ++mi) {
            int row = wr * 64 + mi * 16 + (lane & 15);
            int ps = ls ^ ((row >> 1) & 3);
            af[mi] = *(const short8*)(ab + row * BK + ps * 8);
        }
#pragma unroll
        for (int ni = 0; ni < 4; ++ni) {
            int row = wc * 64 + ni * 16 + (lane & 15);
            int ps = ls ^ ((row >> 1) & 3);
            wf[ni] = *(const short8*)(wb + row * BK + ps * 8);
        }
#pragma unroll
        for (int mi = 0; mi < 4; ++mi)
#pragma unroll
            for (int ni = 0; ni < 4; ++ni)
                acc[mi][ni] = __builtin_amdgcn_mfma_f32_16x16x32_bf16(
                    af[mi], wf[ni], acc[mi][ni], 0, 0, 0);
        __syncthreads();
    }

#pragma unroll
    for (int mi = 0; mi < 4; ++mi)
#pragma unroll
        for (int ni = 0; ni < 4; ++ni)
#pragma unroll
            for (int r = 0; r < 4; ++r) {
                int m = m0 + wr * 64 + mi * 16 + (lane >> 4) * 4 + r;
                int n = n0 + wc * 64 + ni * 16 + (lane & 15);
                outp[(size_t)m * DMODEL + n] = acc[mi][ni][r] + bias[n];
            }
}

// ---------------- flash attention v5: swapped 32x32 QK^T, shfl_xor exchanges ----
// 1024 blocks (16 qt x 64 bh), 256 thr (4 waves x 32 q-rows).
// Q arrives PRE-SCALED by 0.125*log2(e) -> scores are exp2-ready, no per-elem mul.
// Softmax in-register; cross-half ops via __shfl_xor(·,32) (R7-verified).
// Defer-max: skip rescale while tm - m <= 8 (log2 units; p <= 256, exact scaling).
// P->PV A-frags: own/pay selects + 2 shfl_xor per 16-key chunk (R7-verified).
__global__ __launch_bounds__(256) void attn_kernel(const u16* __restrict__ Q,
                                                   const u16* __restrict__ Kx,
                                                   const u16* __restrict__ Vt,
                                                   u16* __restrict__ O) {
    __shared__ __align__(16) u16 Ks[2][64 * 64];
    __shared__ __align__(16) u16 Vs[2][64 * 64];

    const int tid  = threadIdx.x;
    const int lane = tid & 63;
    const int wave = tid >> 6;
    const int hx   = lane >> 5;     // lane half
    const int ql   = lane & 31;     // q column

    // XCD-aware remap (xcd owns 8 bh = 4MB KV = its L2), heavy q-tiles first (LPT)
    const int wgid = blockIdx.x;
    const int xcd  = wgid & 7;
    const int idx  = wgid >> 3;
    const int bh   = xcd * 8 + (idx & 7);
    const int qt   = 15 - (idx >> 3);
    const int b    = bh >> 4;
    const int hh   = bh & 15;

    const size_t base = (size_t)bh * S_LEN * DKH;
    const u16* Qb = Q  + base;
    const u16* Kb = Kx + base;
    const u16* Vb = Vt + base;      // [DK][S]

    const int q0 = qt * 128;
    const int qw = q0 + wave * 32;
    const int qrow = qw + ql;       // this lane's q (softmax state owner)

    // Q as MFMA B-operand: col=lane&31=q, k = 16c + 8*hx + j
    short8 qf[4];
#pragma unroll
    for (int c = 0; c < 4; ++c)
        qf[c] = *(const short8*)(Qb + (size_t)qrow * DKH + c * 16 + hx * 8);

    f32x16 acc[2] = {};             // O[q_local][dk = 32n + ql]
    float m = -1e30f, l = 0.f;

    auto stage = [&](int buf, int t) {
#pragma unroll
        for (int j = 0; j < 2; ++j) {
            int c = j * 256 + tid, wu = j * 256 + (tid & 192);
            int row = c >> 3, slot = c & 7;
            int sg = slot ^ (row & 7);
            gload_lds16(Kb + (size_t)(t * 64 + row) * DKH + sg * 8, &Ks[buf][wu * 8]);
        }
#pragma unroll
        for (int j = 0; j < 2; ++j) {
            int c = j * 256 + tid, wu = j * 256 + (tid & 192);
            int row = c >> 3, slot = c & 7;
            int sg = slot ^ (row & 7);
            gload_lds16(Vb + (size_t)row * S_LEN + t * 64 + sg * 8, &Vs[buf][wu * 8]);
        }
    };

    const int nt = 2 * (qt + 1);
    const int qmax_w = qw + 31;

    stage(0, 0);
    __syncthreads();

    for (int t = 0; t < nt; ++t) {
        const int cur = t & 1;
        if (t + 1 < nt) stage(cur ^ 1, t + 1);

        if (t * 64 <= qmax_w) {
            const u16* kb = Ks[cur];
            const u16* vb = Vs[cur];
            const int smax = (t * 64 + 32 <= qmax_w) ? 2 : 1;

            // ---- QK^T swapped: sc[s] = S^T[key 32s..][q]  (already exp2-scaled) ----
            f32x16 sc[2];
#pragma unroll
            for (int s = 0; s < 2; ++s) if (s < smax) {
                f32x16 z = {};
#pragma unroll
                for (int c = 0; c < 4; ++c) {
                    int row = s * 32 + ql;              // key row in LDS
                    int ps = (2 * c + hx) ^ (row & 7);
                    short8 kf = *(const short8*)(kb + row * 64 + ps * 8);
                    z = __builtin_amdgcn_mfma_f32_32x32x16_bf16(kf, qf[c], z, 0, 0, 0);
                }
                sc[s] = z;
            }

            // ---- causal mask (rare tiles) ----
            if ((t * 64 + 63) > qw) {
                const int kbase = t * 64 + hx * 4;
#pragma unroll
                for (int s = 0; s < 2; ++s) if (s < smax) {
#pragma unroll
                    for (int r = 0; r < 16; ++r) {
                        int key = kbase + 32 * s + (r & 3) + 8 * (r >> 2);
                        if (key > qrow) sc[s][r] = -1e30f;
                    }
                }
            }

            // ---- row max (in-lane 4-chain tree + one cross-half shfl) ----
            float t0 = -1e30f, t1 = -1e30f, t2 = -1e30f, t3 = -1e30f;
#pragma unroll
            for (int s = 0; s < 2; ++s) if (s < smax) {
#pragma unroll
                for (int r = 0; r < 16; r += 4) {
                    t0 = fmaxf(t0, sc[s][r]);
                    t1 = fmaxf(t1, sc[s][r + 1]);
                    t2 = fmaxf(t2, sc[s][r + 2]);
                    t3 = fmaxf(t3, sc[s][r + 3]);
                }
            }
            float tm = fmaxf(fmaxf(t0, t1), fmaxf(t2, t3));
            tm = fmaxf(tm, __shfl_xor(tm, 32));

            // ---- defer-max: rescale only when max grew by > 8 (log2) ----
            if (!__all(tm - m <= 8.0f)) {
                float mn = fmaxf(m, tm);
                float alpha = exp2f(m - mn);
                m = mn; l *= alpha;
#pragma unroll
                for (int r = 0; r < 16; ++r) {
                    int qloc = (r & 3) + 8 * (r >> 2) + 4 * hx;
                    float ar = __shfl(alpha, qloc);
                    acc[0][r] *= ar;
                    acc[1][r] *= ar;
                }
            }

            // ---- exp2 + row sum ----
            float r0 = 0.f, r1 = 0.f;
#pragma unroll
            for (int s = 0; s < 2; ++s) if (s < smax) {
#pragma unroll
                for (int r = 0; r < 16; r += 2) {
                    float p0 = exp2f(sc[s][r] - m);
                    float p1 = exp2f(sc[s][r + 1] - m);
                    sc[s][r] = p0; sc[s][r + 1] = p1;
                    r0 += p0; r1 += p1;
                }
            }
            float rsum = r0 + r1;
            rsum += __shfl_xor(rsum, 32);
            l += rsum;

            // ---- pack P: pk[s][blk][h2] = keys 32s+8blk+4hx+2h2+{0,1} ----
            u32 pk[2][4][2];
#pragma unroll
            for (int s = 0; s < 2; ++s) if (s < smax) {
#pragma unroll
                for (int blk = 0; blk < 4; ++blk) {
                    pk[s][blk][0] = cvt_pk_bf16(sc[s][4 * blk],     sc[s][4 * blk + 1]);
                    pk[s][blk][1] = cvt_pk_bf16(sc[s][4 * blk + 2], sc[s][4 * blk + 3]);
                }
            }

            // ---- PV: A-frag (keys 16t4+8hx+j) via own/pay selects + shfl_xor(32) ----
#pragma unroll
            for (int t4 = 0; t4 < 4; ++t4) if (t4 < 2 * smax) {
                int s  = t4 >> 1;
                int bb = 2 * (t4 & 1);
                u32 own0 = hx ? pk[s][bb + 1][0] : pk[s][bb][0];
                u32 own1 = hx ? pk[s][bb + 1][1] : pk[s][bb][1];
                u32 pay0 = hx ? pk[s][bb][0]     : pk[s][bb + 1][0];
                u32 pay1 = hx ? pk[s][bb][1]     : pk[s][bb + 1][1];
                u32 rcv0 = __shfl_xor(pay0, 32);
                u32 rcv1 = __shfl_xor(pay1, 32);
                u32x4 aw;
                aw.x = hx ? rcv0 : own0;
                aw.y = hx ? rcv1 : own1;
                aw.z = hx ? own0 : rcv0;
                aw.w = hx ? own1 : rcv1;
                short8 pa = __builtin_bit_cast(short8, aw);
#pragma unroll
                for (int n = 0; n < 2; ++n) {
                    int row = 32 * n + ql;              // dk row in V^T LDS
                    int ps = (2 * t4 + hx) ^ (row & 7);
                    short8 vf = *(const short8*)(vb + row * 64 + ps * 8);
                    acc[n] = __builtin_amdgcn_mfma_f32_32x32x16_bf16(pa, vf, acc[n], 0, 0, 0);
                }
            }
        }
        __syncthreads();
    }

    // ---- epilogue ----
    float inv = 1.0f / l;
#pragma unroll
    for (int r = 0; r < 16; ++r) {
        int qloc = (r & 3) + 8 * (r >> 2) + 4 * hx;
        float li = __shfl(inv, qloc);
        size_t obase = ((size_t)b * S_LEN + (qw + qloc)) * DMODEL + hh * 64;
        O[obase + ql]      = f2bf(acc[0][r] * li);
        O[obase + 32 + ql] = f2bf(acc[1][r] * li);
    }
}

// ---------------- launcher ----------------
extern "C" void kernel_launch(void* const* d_in, const int* in_sizes, int n_in,
                              void* d_out, int out_size, void* d_ws, size_t ws_size,
                              hipStream_t stream) {
    const float* x  = (const float*)d_in[0];
    const float* wq = (const float*)d_in[1];
    const float* wk = (const float*)d_in[2];
    const float* wv = (const float*)d_in[3];
    const float* wo = (const float*)d_in[4];
    const float* bo = (const float*)d_in[5];

    const size_t XB = (size_t)BATCH * S_LEN * DMODEL * 2;  // 16 MB
    const size_t WB = (size_t)DMODEL * DMODEL * 2;         // 2 MB

    char* p = (char*)d_ws;
    u16* xb   = (u16*)p; p += XB;      // reused as attention output Od
    u16* wqkv = (u16*)p; p += 3 * WB;  // wq|wk|wv rows 0..3071
    u16* wob  = (u16*)p; p += WB;
    u16* Qd   = (u16*)p; p += XB;
    u16* Kd   = (u16*)p; p += XB;
    u16* Vtd  = (u16*)p; p += XB;
    u16* Od   = xb;
    // total workspace: 4*16MB + 4*2MB = 72 MB

    cast_kernel<<<2048, 256, 0, stream>>>(x, wq, wk, wv, wo, xb, wqkv, wob);

    gemm_qkv<<<dim3(GM / BM, 3072 / BN), 256, 0, stream>>>(xb, wqkv, Qd, Kd, Vtd);

    attn_kernel<<<1024, 256, 0, stream>>>(Qd, Kd, Vtd, Od);

    gemm_out<<<dim3(GM / BM, DMODEL / BN), 256, 0, stream>>>(Od, wob, (float*)d_out, bo);
}